// Round 1
// baseline (91.680 us; speedup 1.0000x reference)
//
#include <hip/hip_runtime.h>
#include <hip/hip_bf16.h>

#define B_SZ 16384
#define SRCN 200
#define CAT  10
#define IN   2000
#define KPAD 2048
#define EPSF 1e-10f

typedef short  short8 __attribute__((ext_vector_type(8)));
typedef float  f32x4  __attribute__((ext_vector_type(4)));

// round-to-nearest-even f32 -> bf16 (bit trick)
__device__ __forceinline__ short f2bf(float f) {
    union { float f; unsigned u; } v; v.f = f;
    unsigned r = (v.u + 0x7fffu + ((v.u >> 16) & 1u)) >> 16;
    return (short)r;
}

// ---------------------------------------------------------------------------
// Prep: build bf16 coefficient tables logp_t[16][2048], wyc_t[16][2048]
// (zero-padded), compute l1 = sum|W_yc|, zero the loss accumulators.
// ---------------------------------------------------------------------------
__global__ void prep_kernel(const float* __restrict__ W_rec,
                            const float* __restrict__ b_rec,
                            const float* __restrict__ W_yc,
                            short* __restrict__ logp_t,
                            short* __restrict__ wyc_t,
                            double* __restrict__ acc) {
    if (blockIdx.x == gridDim.x - 1) {
        // l1 over 20000 elements + zero accumulators
        float p = 0.f;
        for (int i = threadIdx.x; i < IN * CAT; i += blockDim.x) p += fabsf(W_yc[i]);
        __shared__ float red[4];
        for (int o = 32; o; o >>= 1) p += __shfl_down(p, o, 64);
        if ((threadIdx.x & 63) == 0) red[threadIdx.x >> 6] = p;
        __syncthreads();
        if (threadIdx.x == 0) {
            acc[0] = 0.0;
            acc[1] = 0.0;
            acc[2] = (double)(red[0] + red[1] + red[2] + red[3]);
        }
        return;
    }
    int tid = blockIdx.x * blockDim.x + threadIdx.x;   // 0 .. 16*2048-1
    int n = tid >> 11;         // padded row 0..15
    int k = tid & 2047;        // padded col 0..2047
    short wv = 0, lv = 0;
    if (n < CAT && k < IN) {
        wv = f2bf(W_yc[k * CAT + n]);
        int base = (k / CAT) * CAT;          // this source's block of 10
        float lg[CAT];
        float m = -1e30f;
        #pragma unroll
        for (int i = 0; i < CAT; i++) {
            lg[i] = W_rec[n * IN + base + i] + b_rec[base + i];
            m = fmaxf(m, lg[i]);
        }
        float s = 0.f;
        #pragma unroll
        for (int i = 0; i < CAT; i++) s += expf(lg[i] - m);
        float myl = W_rec[n * IN + k] + b_rec[k];
        float pp = expf(myl - m) / s;
        lv = f2bf(logf(EPSF + pp));
    }
    wyc_t[n * KPAD + k] = wv;
    logp_t[n * KPAD + k] = lv;
}

// ---------------------------------------------------------------------------
// Main: per block = one 16-row tile; 2 waves split K (0..1023 / 1024..2047).
// Per k-iter each lane: 32B x + 32B mask (f32), 16B logp + 16B wyc (bf16),
// cvt to bf16, 2 MFMAs. Epilogue (wave 0): softmax over 16-lane groups,
// y write, loss partials -> f64 atomics.
// ---------------------------------------------------------------------------
__global__ __launch_bounds__(128) void main_kernel(
        const float* __restrict__ x, const float* __restrict__ mask,
        const float* __restrict__ y_target, const float* __restrict__ b_yc,
        const short* __restrict__ logp_t, const short* __restrict__ wyc_t,
        float* __restrict__ out, double* __restrict__ acc) {
    const int l   = threadIdx.x & 63;
    const int w   = threadIdx.x >> 6;
    const int r0  = blockIdx.x * 16;
    const int m16 = l & 15;      // A row / D col
    const int kg  = l >> 4;      // k subgroup

    f32x4 accR = {0.f, 0.f, 0.f, 0.f};
    f32x4 accY = {0.f, 0.f, 0.f, 0.f};

    const size_t xbase = (size_t)(r0 + m16) * IN;
    const short* lpB = logp_t + m16 * KPAD;
    const short* wyB = wyc_t + m16 * KPAD;

    #pragma unroll 4
    for (int t = 0; t < 32; ++t) {
        const int kt = w * 32 + t;
        const int k0 = kt * 32 + kg * 8;
        const int kc = (k0 + 8 <= IN) ? k0 : 0;   // clamp; padded coefs are 0
        const float4* xp = reinterpret_cast<const float4*>(x + xbase + kc);
        const float4* mp = reinterpret_cast<const float4*>(mask + xbase + kc);
        float4 xa = xp[0], xb = xp[1];
        float4 ma = mp[0], mb = mp[1];
        float xs[8] = {xa.x, xa.y, xa.z, xa.w, xb.x, xb.y, xb.z, xb.w};
        float ms[8] = {ma.x, ma.y, ma.z, ma.w, mb.x, mb.y, mb.z, mb.w};
        short8 fx, fxm;
        #pragma unroll
        for (int e = 0; e < 8; e++) {
            fx[e]  = f2bf(xs[e]);
            fxm[e] = f2bf(xs[e] * ms[e]);
        }
        const short8 bR = *reinterpret_cast<const short8*>(lpB + k0);
        const short8 bW = *reinterpret_cast<const short8*>(wyB + k0);
        accR = __builtin_amdgcn_mfma_f32_16x16x32_bf16(fxm, bR, accR, 0, 0, 0);
        accY = __builtin_amdgcn_mfma_f32_16x16x32_bf16(fx,  bW, accY, 0, 0, 0);
    }

    // combine K-split halves through LDS
    __shared__ float lds[64 * 8];
    if (w == 1) {
        #pragma unroll
        for (int q = 0; q < 4; q++) {
            lds[l * 8 + q]     = accR[q];
            lds[l * 8 + 4 + q] = accY[q];
        }
    }
    __syncthreads();
    if (w != 0) return;
    #pragma unroll
    for (int q = 0; q < 4; q++) {
        accR[q] += lds[l * 8 + q];
        accY[q] += lds[l * 8 + 4 + q];
    }

    // epilogue: D mapping col = l&15, row = (l>>4)*4 + q
    const bool valid = (m16 < CAT);
    const float byc = valid ? b_yc[m16] : 0.f;
    float a_cls = 0.f, a_kl = 0.f;
    #pragma unroll
    for (int q = 0; q < 4; q++) {
        const int grow = r0 + kg * 4 + q;
        float z = accY[q] + byc;
        float zz = valid ? z : -1e30f;
        #pragma unroll
        for (int o = 1; o < 16; o <<= 1) zz = fmaxf(zz, __shfl_xor(zz, o, 64));
        float e = valid ? __expf(z - zz) : 0.f;
        float s = e;
        #pragma unroll
        for (int o = 1; o < 16; o <<= 1) s += __shfl_xor(s, o, 64);
        float y = e / s;
        float recon = -accR[q] * (1.f / IN);
        float cls = y * recon;
        float kl = 0.f;
        if (valid) {
            float yt = y_target[(size_t)grow * CAT + m16];
            kl = y * (logf(EPSF + y) - logf(EPSF + yt));
            out[(size_t)grow * CAT + m16] = y;
        }
        #pragma unroll
        for (int o = 1; o < 16; o <<= 1) {
            cls += __shfl_xor(cls, o, 64);
            kl  += __shfl_xor(kl, o, 64);
        }
        if (m16 == 0) { a_cls += cls; a_kl += kl; }
    }
    float vc = (m16 == 0) ? a_cls : 0.f;
    float vk = (m16 == 0) ? a_kl  : 0.f;
    vc += __shfl_xor(vc, 16, 64); vc += __shfl_xor(vc, 32, 64);
    vk += __shfl_xor(vk, 16, 64); vk += __shfl_xor(vk, 32, 64);
    if (l == 0) {
        atomicAdd(&acc[0], (double)vc);
        atomicAdd(&acc[1], (double)vk);
    }
}

__global__ void final_kernel(const double* __restrict__ acc,
                             float* __restrict__ out) {
    if (threadIdx.x == 0) {
        double loss = acc[0] / (double)B_SZ
                    + 1e-4 * (acc[1] / (double)B_SZ)
                    + (0.005 / (double)SRCN / (double)CAT / (double)CAT) * acc[2];
        out[(size_t)B_SZ * CAT] = (float)loss;
    }
}

extern "C" void kernel_launch(void* const* d_in, const int* in_sizes, int n_in,
                              void* d_out, int out_size, void* d_ws, size_t ws_size,
                              hipStream_t stream) {
    const float* x        = (const float*)d_in[0];
    const float* mask     = (const float*)d_in[1];
    const float* y_target = (const float*)d_in[2];
    const float* W_rec    = (const float*)d_in[3];
    const float* b_rec    = (const float*)d_in[4];
    const float* W_yc     = (const float*)d_in[5];
    const float* b_yc     = (const float*)d_in[6];
    float* out  = (float*)d_out;
    double* acc = (double*)d_ws;
    short* logp_t = (short*)((char*)d_ws + 256);
    short* wyc_t  = logp_t + 16 * KPAD;

    // tables: 128 blocks cover 16*2048 entries; last block does l1 + zeroing
    prep_kernel<<<129, 256, 0, stream>>>(W_rec, b_rec, W_yc, logp_t, wyc_t, acc);
    // 1024 row-tiles of 16 rows; 2 waves per block split K
    main_kernel<<<1024, 128, 0, stream>>>(x, mask, y_target, b_yc,
                                          logp_t, wyc_t, out, acc);
    final_kernel<<<1, 64, 0, stream>>>(acc, out);
}

// Round 2
// 85.355 us; speedup vs baseline: 1.0741x; 1.0741x over previous
//
#include <hip/hip_runtime.h>
#include <hip/hip_bf16.h>

#define B_SZ 16384
#define SRCN 200
#define CAT  10
#define IN   2000
#define KPAD 2048
#define EPSF 1e-10f

typedef short  short8 __attribute__((ext_vector_type(8)));
typedef float  f32x4  __attribute__((ext_vector_type(4)));

// round-to-nearest-even f32 -> bf16 (bit trick)
__device__ __forceinline__ short f2bf(float f) {
    union { float f; unsigned u; } v; v.f = f;
    unsigned r = (v.u + 0x7fffu + ((v.u >> 16) & 1u)) >> 16;
    return (short)r;
}

// ---------------------------------------------------------------------------
// Prep: build bf16 coefficient tables logp_t[16][2048], wyc_t[16][2048]
// (zero-padded), compute l1 = sum|W_yc|, zero the loss accumulators.
// ---------------------------------------------------------------------------
__global__ void prep_kernel(const float* __restrict__ W_rec,
                            const float* __restrict__ b_rec,
                            const float* __restrict__ W_yc,
                            short* __restrict__ logp_t,
                            short* __restrict__ wyc_t,
                            double* __restrict__ acc) {
    if (blockIdx.x == gridDim.x - 1) {
        float p = 0.f;
        for (int i = threadIdx.x; i < IN * CAT; i += blockDim.x) p += fabsf(W_yc[i]);
        __shared__ float red[4];
        for (int o = 32; o; o >>= 1) p += __shfl_down(p, o, 64);
        if ((threadIdx.x & 63) == 0) red[threadIdx.x >> 6] = p;
        __syncthreads();
        if (threadIdx.x == 0) {
            acc[0] = 0.0;
            acc[1] = 0.0;
            acc[2] = (double)(red[0] + red[1] + red[2] + red[3]);
        }
        return;
    }
    int tid = blockIdx.x * blockDim.x + threadIdx.x;   // 0 .. 16*2048-1
    int n = tid >> 11;         // padded row 0..15
    int k = tid & 2047;        // padded col 0..2047
    short wv = 0, lv = 0;
    if (n < CAT && k < IN) {
        wv = f2bf(W_yc[k * CAT + n]);
        int base = (k / CAT) * CAT;          // this source's block of 10
        float lg[CAT];
        float m = -1e30f;
        #pragma unroll
        for (int i = 0; i < CAT; i++) {
            lg[i] = W_rec[n * IN + base + i] + b_rec[base + i];
            m = fmaxf(m, lg[i]);
        }
        float s = 0.f;
        #pragma unroll
        for (int i = 0; i < CAT; i++) s += expf(lg[i] - m);
        float myl = W_rec[n * IN + k] + b_rec[k];
        float pp = expf(myl - m) / s;
        lv = f2bf(logf(EPSF + pp));
    }
    wyc_t[n * KPAD + k] = wv;
    logp_t[n * KPAD + k] = lv;
}

// ---------------------------------------------------------------------------
// Main: per block = one 16-row tile; 8 waves split K (256 elems each).
// Per k-iter each lane: 32B x + 32B mask (f32), 16B logp + 16B wyc (bf16),
// cvt to bf16, 2 MFMAs. 8-wave LDS reduction, wave-0 epilogue: softmax over
// 16-lane groups, y write, loss partials -> f64 atomics.
// ---------------------------------------------------------------------------
__global__ __launch_bounds__(512) void main_kernel(
        const float* __restrict__ x, const float* __restrict__ mask,
        const float* __restrict__ y_target, const float* __restrict__ b_yc,
        const short* __restrict__ logp_t, const short* __restrict__ wyc_t,
        float* __restrict__ out, double* __restrict__ acc) {
    const int l   = threadIdx.x & 63;
    const int w   = threadIdx.x >> 6;   // 0..7
    const int r0  = blockIdx.x * 16;
    const int m16 = l & 15;      // A row / D col
    const int kg  = l >> 4;      // k subgroup

    f32x4 accR = {0.f, 0.f, 0.f, 0.f};
    f32x4 accY = {0.f, 0.f, 0.f, 0.f};

    const size_t xbase = (size_t)(r0 + m16) * IN;
    const short* lpB = logp_t + m16 * KPAD;
    const short* wyB = wyc_t + m16 * KPAD;

    #pragma unroll 4
    for (int t = 0; t < 8; ++t) {
        const int kt = w * 8 + t;                 // 0..63
        const int k0 = kt * 32 + kg * 8;          // 0..2040
        const int kc = (k0 + 8 <= IN) ? k0 : 0;   // clamp; padded coefs are 0
        const float4* xp = reinterpret_cast<const float4*>(x + xbase + kc);
        const float4* mp = reinterpret_cast<const float4*>(mask + xbase + kc);
        float4 xa = xp[0], xb = xp[1];
        float4 ma = mp[0], mb = mp[1];
        float xs[8] = {xa.x, xa.y, xa.z, xa.w, xb.x, xb.y, xb.z, xb.w};
        float ms[8] = {ma.x, ma.y, ma.z, ma.w, mb.x, mb.y, mb.z, mb.w};
        short8 fx, fxm;
        #pragma unroll
        for (int e = 0; e < 8; e++) {
            fx[e]  = f2bf(xs[e]);
            fxm[e] = f2bf(xs[e] * ms[e]);
        }
        const short8 bR = *reinterpret_cast<const short8*>(lpB + k0);
        const short8 bW = *reinterpret_cast<const short8*>(wyB + k0);
        accR = __builtin_amdgcn_mfma_f32_16x16x32_bf16(fxm, bR, accR, 0, 0, 0);
        accY = __builtin_amdgcn_mfma_f32_16x16x32_bf16(fx,  bW, accY, 0, 0, 0);
    }

    // combine the 8 K-split partials through LDS (pad stride 9 -> no 16-way
    // bank conflicts on the wave-0 gather)
    __shared__ float lds[8][64][9];
    #pragma unroll
    for (int q = 0; q < 4; q++) {
        lds[w][l][q]     = accR[q];
        lds[w][l][4 + q] = accY[q];
    }
    __syncthreads();
    if (w != 0) return;
    f32x4 sR = {0.f, 0.f, 0.f, 0.f};
    f32x4 sY = {0.f, 0.f, 0.f, 0.f};
    #pragma unroll
    for (int w2 = 0; w2 < 8; w2++) {
        #pragma unroll
        for (int q = 0; q < 4; q++) {
            sR[q] += lds[w2][l][q];
            sY[q] += lds[w2][l][4 + q];
        }
    }

    // epilogue: D mapping col = l&15, row = (l>>4)*4 + q
    const bool valid = (m16 < CAT);
    const float byc = valid ? b_yc[m16] : 0.f;
    float a_cls = 0.f, a_kl = 0.f;
    #pragma unroll
    for (int q = 0; q < 4; q++) {
        const int grow = r0 + kg * 4 + q;
        float z = sY[q] + byc;
        float zz = valid ? z : -1e30f;
        #pragma unroll
        for (int o = 1; o < 16; o <<= 1) zz = fmaxf(zz, __shfl_xor(zz, o, 64));
        float e = valid ? __expf(z - zz) : 0.f;
        float s = e;
        #pragma unroll
        for (int o = 1; o < 16; o <<= 1) s += __shfl_xor(s, o, 64);
        float y = e / s;
        float recon = -sR[q] * (1.f / IN);
        float cls = y * recon;
        float kl = 0.f;
        if (valid) {
            float yt = y_target[(size_t)grow * CAT + m16];
            kl = y * (logf(EPSF + y) - logf(EPSF + yt));
            out[(size_t)grow * CAT + m16] = y;
        }
        #pragma unroll
        for (int o = 1; o < 16; o <<= 1) {
            cls += __shfl_xor(cls, o, 64);
            kl  += __shfl_xor(kl, o, 64);
        }
        if (m16 == 0) { a_cls += cls; a_kl += kl; }
    }
    float vc = (m16 == 0) ? a_cls : 0.f;
    float vk = (m16 == 0) ? a_kl  : 0.f;
    vc += __shfl_xor(vc, 16, 64); vc += __shfl_xor(vc, 32, 64);
    vk += __shfl_xor(vk, 16, 64); vk += __shfl_xor(vk, 32, 64);
    if (l == 0) {
        atomicAdd(&acc[0], (double)vc);
        atomicAdd(&acc[1], (double)vk);
    }
}

__global__ void final_kernel(const double* __restrict__ acc,
                             float* __restrict__ out) {
    if (threadIdx.x == 0) {
        double loss = acc[0] / (double)B_SZ
                    + 1e-4 * (acc[1] / (double)B_SZ)
                    + (0.005 / (double)SRCN / (double)CAT / (double)CAT) * acc[2];
        out[(size_t)B_SZ * CAT] = (float)loss;
    }
}

extern "C" void kernel_launch(void* const* d_in, const int* in_sizes, int n_in,
                              void* d_out, int out_size, void* d_ws, size_t ws_size,
                              hipStream_t stream) {
    const float* x        = (const float*)d_in[0];
    const float* mask     = (const float*)d_in[1];
    const float* y_target = (const float*)d_in[2];
    const float* W_rec    = (const float*)d_in[3];
    const float* b_rec    = (const float*)d_in[4];
    const float* W_yc     = (const float*)d_in[5];
    const float* b_yc     = (const float*)d_in[6];
    float* out  = (float*)d_out;
    double* acc = (double*)d_ws;
    short* logp_t = (short*)((char*)d_ws + 256);
    short* wyc_t  = logp_t + 16 * KPAD;

    // tables: 128 blocks cover 16*2048 entries; last block does l1 + zeroing
    prep_kernel<<<129, 256, 0, stream>>>(W_rec, b_rec, W_yc, logp_t, wyc_t, acc);
    // 1024 row-tiles of 16 rows; 8 waves per block split K
    main_kernel<<<1024, 512, 0, stream>>>(x, mask, y_target, b_yc,
                                          logp_t, wyc_t, out, acc);
    final_kernel<<<1, 64, 0, stream>>>(acc, out);
}

// Round 3
// 85.306 us; speedup vs baseline: 1.0747x; 1.0006x over previous
//
#include <hip/hip_runtime.h>
#include <hip/hip_bf16.h>

#define B_SZ 16384
#define SRCN 200
#define CAT  10
#define IN   2000
#define KPAD 2048
#define CHUNK 512          // f32 columns staged per chunk
#define NCH   4            // 4 * 512 = 2048 (zero-padded K)
#define TSZ   16384        // bytes per (tensor) LDS table: 16 rows * 512 cols * 2B
#define EPSF 1e-10f

typedef short  short8 __attribute__((ext_vector_type(8)));
typedef short  short4v __attribute__((ext_vector_type(4)));
typedef float  f32x4  __attribute__((ext_vector_type(4)));

// round-to-nearest-even f32 -> bf16 (bit trick)
__device__ __forceinline__ short f2bf(float f) {
    union { float f; unsigned u; } v; v.f = f;
    unsigned r = (v.u + 0x7fffu + ((v.u >> 16) & 1u)) >> 16;
    return (short)r;
}

// swizzled byte offset within one LDS table: row stride 1024B (mod 128 == 0,
// bank-neutral); XOR spreads the 16B fragment slots across all 8 bank groups.
__device__ __forceinline__ int swz(int row, int colByte) {
    return row * 1024 + (colByte ^ ((row & 7) << 4));
}

// ---------------------------------------------------------------------------
// Prep: build bf16 coefficient tables logp_t[16][2048], wyc_t[16][2048]
// (zero-padded), compute l1 = sum|W_yc|, zero the loss accumulators.
// ---------------------------------------------------------------------------
__global__ void prep_kernel(const float* __restrict__ W_rec,
                            const float* __restrict__ b_rec,
                            const float* __restrict__ W_yc,
                            short* __restrict__ logp_t,
                            short* __restrict__ wyc_t,
                            double* __restrict__ acc) {
    if (blockIdx.x == gridDim.x - 1) {
        float p = 0.f;
        for (int i = threadIdx.x; i < IN * CAT; i += blockDim.x) p += fabsf(W_yc[i]);
        __shared__ float red[4];
        for (int o = 32; o; o >>= 1) p += __shfl_down(p, o, 64);
        if ((threadIdx.x & 63) == 0) red[threadIdx.x >> 6] = p;
        __syncthreads();
        if (threadIdx.x == 0) {
            acc[0] = 0.0;
            acc[1] = 0.0;
            acc[2] = (double)(red[0] + red[1] + red[2] + red[3]);
        }
        return;
    }
    int tid = blockIdx.x * blockDim.x + threadIdx.x;   // 0 .. 16*2048-1
    int n = tid >> 11;         // padded row 0..15
    int k = tid & 2047;        // padded col 0..2047
    short wv = 0, lv = 0;
    if (n < CAT && k < IN) {
        wv = f2bf(W_yc[k * CAT + n]);
        int base = (k / CAT) * CAT;          // this source's block of 10
        float lg[CAT];
        float m = -1e30f;
        #pragma unroll
        for (int i = 0; i < CAT; i++) {
            lg[i] = W_rec[n * IN + base + i] + b_rec[base + i];
            m = fmaxf(m, lg[i]);
        }
        float s = 0.f;
        #pragma unroll
        for (int i = 0; i < CAT; i++) s += expf(lg[i] - m);
        float myl = W_rec[n * IN + k] + b_rec[k];
        float pp = expf(myl - m) / s;
        lv = f2bf(logf(EPSF + pp));
    }
    wyc_t[n * KPAD + k] = wv;
    logp_t[n * KPAD + k] = lv;
}

// ---------------------------------------------------------------------------
// Main: block = 16 batch rows, 8 waves. Per 512-col chunk:
//   stage: coalesced f32 loads of x/mask (1KB contiguous per wave instr),
//          convert to bf16 {x, x*mask}, swizzled LDS store (32KB total).
//   compute: each wave owns a 64-col K-slice; A-fragments via ds_read_b128
//          from LDS, B-fragments (logp/wyc, L2-resident) from global; 2 MFMAs.
// 8-wave LDS reduction (reusing the tile buffer), wave-0 epilogue: softmax,
// y write, loss partials -> f64 atomics.
// ---------------------------------------------------------------------------
__global__ __launch_bounds__(512, 8) void main_kernel(
        const float* __restrict__ x, const float* __restrict__ mask,
        const float* __restrict__ y_target, const float* __restrict__ b_yc,
        const short* __restrict__ logp_t, const short* __restrict__ wyc_t,
        float* __restrict__ out, double* __restrict__ acc) {
    __shared__ __attribute__((aligned(16))) char smem[2 * TSZ];   // 32 KB

    const int l   = threadIdx.x & 63;
    const int w   = threadIdx.x >> 6;   // 0..7
    const int r0  = blockIdx.x * 16;
    const int m16 = l & 15;             // A row / D col
    const int kg  = l >> 4;             // k subgroup

    f32x4 accR = {0.f, 0.f, 0.f, 0.f};
    f32x4 accY = {0.f, 0.f, 0.f, 0.f};

    const short* lpB = logp_t + m16 * KPAD;
    const short* wyB = wyc_t + m16 * KPAD;

    for (int c = 0; c < NCH; ++c) {
        // ---- stage chunk c: wave w covers rows w and w+8, 2 groups of 256 f32
        #pragma unroll
        for (int r = 0; r < 2; ++r) {
            const int row = w + r * 8;
            const size_t gb = (size_t)(r0 + row) * IN;
            const int col0 = c * CHUNK + l * 4;
            const int col1 = col0 + 256;
            const bool ok0 = (col0 + 3) < IN;
            const bool ok1 = (col1 + 3) < IN;
            const float4 x0 = *reinterpret_cast<const float4*>(x + gb + (ok0 ? col0 : 0));
            const float4 m0 = *reinterpret_cast<const float4*>(mask + gb + (ok0 ? col0 : 0));
            const float4 x1 = *reinterpret_cast<const float4*>(x + gb + (ok1 ? col1 : 0));
            const float4 m1 = *reinterpret_cast<const float4*>(mask + gb + (ok1 ? col1 : 0));
            float xf[8] = {x0.x, x0.y, x0.z, x0.w, x1.x, x1.y, x1.z, x1.w};
            float mf[8] = {m0.x, m0.y, m0.z, m0.w, m1.x, m1.y, m1.z, m1.w};
            short4v xb0, xb1, xm0, xm1;
            #pragma unroll
            for (int e = 0; e < 4; ++e) {
                float a0 = ok0 ? xf[e]     : 0.f;
                float a1 = ok1 ? xf[4 + e] : 0.f;
                xb0[e] = f2bf(a0);
                xb1[e] = f2bf(a1);
                xm0[e] = f2bf(a0 * mf[e]);
                xm1[e] = f2bf(a1 * mf[4 + e]);
            }
            *reinterpret_cast<short4v*>(smem + swz(row, l * 8))             = xb0;
            *reinterpret_cast<short4v*>(smem + swz(row, 512 + l * 8))       = xb1;
            *reinterpret_cast<short4v*>(smem + TSZ + swz(row, l * 8))       = xm0;
            *reinterpret_cast<short4v*>(smem + TSZ + swz(row, 512 + l * 8)) = xm1;
        }
        __syncthreads();

        // ---- compute chunk c: wave w owns local cols [w*64, w*64+64)
        #pragma unroll
        for (int t = 0; t < 2; ++t) {
            const int kl = w * 64 + t * 32 + kg * 8;     // local bf16 col
            const int kglob = c * CHUNK + kl;
            const short8 aX  = *reinterpret_cast<const short8*>(smem + swz(m16, kl * 2));
            const short8 aXM = *reinterpret_cast<const short8*>(smem + TSZ + swz(m16, kl * 2));
            const short8 bRv = *reinterpret_cast<const short8*>(lpB + kglob);
            const short8 bWv = *reinterpret_cast<const short8*>(wyB + kglob);
            accR = __builtin_amdgcn_mfma_f32_16x16x32_bf16(aXM, bRv, accR, 0, 0, 0);
            accY = __builtin_amdgcn_mfma_f32_16x16x32_bf16(aX,  bWv, accY, 0, 0, 0);
        }
        __syncthreads();   // guard next stage overwrite / final reuse
    }

    // combine the 8 K-split partials through LDS (reuse tile buffer; stride 9
    // floats -> no bank conflicts). 8*64*9*4B = 18KB < 32KB.
    float (*red)[64][9] = reinterpret_cast<float (*)[64][9]>(smem);
    #pragma unroll
    for (int q = 0; q < 4; q++) {
        red[w][l][q]     = accR[q];
        red[w][l][4 + q] = accY[q];
    }
    __syncthreads();
    if (w != 0) return;
    f32x4 sR = {0.f, 0.f, 0.f, 0.f};
    f32x4 sY = {0.f, 0.f, 0.f, 0.f};
    #pragma unroll
    for (int w2 = 0; w2 < 8; w2++) {
        #pragma unroll
        for (int q = 0; q < 4; q++) {
            sR[q] += red[w2][l][q];
            sY[q] += red[w2][l][4 + q];
        }
    }

    // epilogue: D mapping col = l&15, row = (l>>4)*4 + q
    const bool valid = (m16 < CAT);
    const float byc = valid ? b_yc[m16] : 0.f;
    float a_cls = 0.f, a_kl = 0.f;
    #pragma unroll
    for (int q = 0; q < 4; q++) {
        const int grow = r0 + kg * 4 + q;
        float z = sY[q] + byc;
        float zz = valid ? z : -1e30f;
        #pragma unroll
        for (int o = 1; o < 16; o <<= 1) zz = fmaxf(zz, __shfl_xor(zz, o, 64));
        float e = valid ? __expf(z - zz) : 0.f;
        float s = e;
        #pragma unroll
        for (int o = 1; o < 16; o <<= 1) s += __shfl_xor(s, o, 64);
        float y = e / s;
        float recon = -sR[q] * (1.f / IN);
        float cls = y * recon;
        float kl = 0.f;
        if (valid) {
            float yt = y_target[(size_t)grow * CAT + m16];
            kl = y * (logf(EPSF + y) - logf(EPSF + yt));
            out[(size_t)grow * CAT + m16] = y;
        }
        #pragma unroll
        for (int o = 1; o < 16; o <<= 1) {
            cls += __shfl_xor(cls, o, 64);
            kl  += __shfl_xor(kl, o, 64);
        }
        if (m16 == 0) { a_cls += cls; a_kl += kl; }
    }
    float vc = (m16 == 0) ? a_cls : 0.f;
    float vk = (m16 == 0) ? a_kl  : 0.f;
    vc += __shfl_xor(vc, 16, 64); vc += __shfl_xor(vc, 32, 64);
    vk += __shfl_xor(vk, 16, 64); vk += __shfl_xor(vk, 32, 64);
    if (l == 0) {
        atomicAdd(&acc[0], (double)vc);
        atomicAdd(&acc[1], (double)vk);
    }
}

__global__ void final_kernel(const double* __restrict__ acc,
                             float* __restrict__ out) {
    if (threadIdx.x == 0) {
        double loss = acc[0] / (double)B_SZ
                    + 1e-4 * (acc[1] / (double)B_SZ)
                    + (0.005 / (double)SRCN / (double)CAT / (double)CAT) * acc[2];
        out[(size_t)B_SZ * CAT] = (float)loss;
    }
}

extern "C" void kernel_launch(void* const* d_in, const int* in_sizes, int n_in,
                              void* d_out, int out_size, void* d_ws, size_t ws_size,
                              hipStream_t stream) {
    const float* x        = (const float*)d_in[0];
    const float* mask     = (const float*)d_in[1];
    const float* y_target = (const float*)d_in[2];
    const float* W_rec    = (const float*)d_in[3];
    const float* b_rec    = (const float*)d_in[4];
    const float* W_yc     = (const float*)d_in[5];
    const float* b_yc     = (const float*)d_in[6];
    float* out  = (float*)d_out;
    double* acc = (double*)d_ws;
    short* logp_t = (short*)((char*)d_ws + 256);
    short* wyc_t  = logp_t + 16 * KPAD;

    // tables: 128 blocks cover 16*2048 entries; last block does l1 + zeroing
    prep_kernel<<<129, 256, 0, stream>>>(W_rec, b_rec, W_yc, logp_t, wyc_t, acc);
    // 1024 row-tiles of 16 rows; staged-LDS MFMA, 4 blocks/CU
    main_kernel<<<1024, 512, 0, stream>>>(x, mask, y_target, b_yc,
                                          logp_t, wyc_t, out, acc);
    final_kernel<<<1, 64, 0, stream>>>(acc, out);
}

// Round 4
// 80.335 us; speedup vs baseline: 1.1412x; 1.0619x over previous
//
#include <hip/hip_runtime.h>
#include <hip/hip_bf16.h>

#define B_SZ 16384
#define SRCN 200
#define CAT  10
#define IN   2000
#define KPAD 2048
#define CHUNKF 256         // f32 columns staged per chunk
#define NCH   8            // 8 * 256 = 2048 (zero-padded K)
#define ROWB  1024         // bytes per row in one LDS tensor buffer (256 f32)
#define TBUF  16384        // one tensor buffer: 16 rows * 1024 B
#define BUFSZ 32768        // x + mask for one chunk
#define EPSF 1e-10f

typedef short  short8 __attribute__((ext_vector_type(8)));
typedef float  f32x4  __attribute__((ext_vector_type(4)));

// round-to-nearest-even f32 -> bf16 (bit trick)
__device__ __forceinline__ short f2bf(float f) {
    union { float f; unsigned u; } v; v.f = f;
    unsigned r = (v.u + 0x7fffu + ((v.u >> 16) & 1u)) >> 16;
    return (short)r;
}

// async global->LDS, 16B per lane; LDS dest = uniform base + lane*16 (m104)
__device__ __forceinline__ void gload16(const void* g, void* l) {
    __builtin_amdgcn_global_load_lds(
        (const __attribute__((address_space(1))) void*)g,
        (__attribute__((address_space(3))) void*)l,
        16, 0, 0);
}

// ---------------------------------------------------------------------------
// Prep: bf16 tables logp_t[16][2048], wyc_t[16][2048] (zero-padded),
// l1 = sum|W_yc|, zero loss accumulators.
// ---------------------------------------------------------------------------
__global__ void prep_kernel(const float* __restrict__ W_rec,
                            const float* __restrict__ b_rec,
                            const float* __restrict__ W_yc,
                            short* __restrict__ logp_t,
                            short* __restrict__ wyc_t,
                            double* __restrict__ acc) {
    if (blockIdx.x == gridDim.x - 1) {
        float p = 0.f;
        for (int i = threadIdx.x; i < IN * CAT; i += blockDim.x) p += fabsf(W_yc[i]);
        __shared__ float red[4];
        for (int o = 32; o; o >>= 1) p += __shfl_down(p, o, 64);
        if ((threadIdx.x & 63) == 0) red[threadIdx.x >> 6] = p;
        __syncthreads();
        if (threadIdx.x == 0) {
            acc[0] = 0.0;
            acc[1] = 0.0;
            acc[2] = (double)(red[0] + red[1] + red[2] + red[3]);
        }
        return;
    }
    int tid = blockIdx.x * blockDim.x + threadIdx.x;   // 0 .. 16*2048-1
    int n = tid >> 11;
    int k = tid & 2047;
    short wv = 0, lv = 0;
    if (n < CAT && k < IN) {
        wv = f2bf(W_yc[k * CAT + n]);
        int base = (k / CAT) * CAT;
        float lg[CAT];
        float m = -1e30f;
        #pragma unroll
        for (int i = 0; i < CAT; i++) {
            lg[i] = W_rec[n * IN + base + i] + b_rec[base + i];
            m = fmaxf(m, lg[i]);
        }
        float s = 0.f;
        #pragma unroll
        for (int i = 0; i < CAT; i++) s += expf(lg[i] - m);
        float myl = W_rec[n * IN + k] + b_rec[k];
        float pp = expf(myl - m) / s;
        lv = f2bf(logf(EPSF + pp));
    }
    wyc_t[n * KPAD + k] = wv;
    logp_t[n * KPAD + k] = lv;
}

// ---------------------------------------------------------------------------
// Main: block = 16 rows, 4 waves. Double-buffered async pipeline:
//   all B fragments preloaded to registers (static-indexed, 128 VGPR);
//   global_load_lds stages x/mask (pre-swizzled per-lane SOURCE -> swizzled
//   LDS layout with linear dest); counted vmcnt(8) + raw s_barrier keeps one
//   full chunk of loads in flight across barriers.
// ---------------------------------------------------------------------------
__global__ __launch_bounds__(256, 2) void main_kernel(
        const float* __restrict__ x, const float* __restrict__ mask,
        const float* __restrict__ y_target, const float* __restrict__ b_yc,
        const short* __restrict__ logp_t, const short* __restrict__ wyc_t,
        float* __restrict__ out, double* __restrict__ acc) {
    __shared__ __attribute__((aligned(16))) char smem[2 * BUFSZ];   // 64 KB

    const int l   = threadIdx.x & 63;
    const int w   = threadIdx.x >> 6;   // 0..3
    const int r0  = blockIdx.x * 16;
    const int m16 = l & 15;             // A row / D col
    const int kg  = l >> 4;             // k subgroup

    const short* lpB = logp_t + m16 * KPAD;
    const short* wyB = wyc_t + m16 * KPAD;

    // ---- B preload: issued BEFORE any stage so stage vmcnt counting is exact
    short8 bR[NCH][2], bW[NCH][2];
    #pragma unroll
    for (int c = 0; c < NCH; ++c) {
        #pragma unroll
        for (int t = 0; t < 2; ++t) {
            const int kglob = c * CHUNKF + w * 64 + t * 32 + kg * 8;
            bR[c][t] = *reinterpret_cast<const short8*>(lpB + kglob);
            bW[c][t] = *reinterpret_cast<const short8*>(wyB + kglob);
        }
    }

    f32x4 accR = {0.f, 0.f, 0.f, 0.f};
    f32x4 accY = {0.f, 0.f, 0.f, 0.f};

    // stage chunk c into buffer b: 8 gload16 per wave (4 rows x 2 tensors).
    // source col-granule = l ^ (row&7)  => LDS ends up XOR-swizzled.
    auto stage = [&](int c, int b) {
        #pragma unroll
        for (int i = 0; i < 4; ++i) {
            const int lr = w * 4 + i;
            const size_t gb = (size_t)(r0 + lr) * IN;
            int srcf = c * CHUNKF + ((l ^ (lr & 7)) << 2);
            if (srcf > IN - 4) srcf = IN - 4;     // tail clamp (pad cols -> B=0)
            gload16(x + gb + srcf,    smem + b * BUFSZ + lr * ROWB);
            gload16(mask + gb + srcf, smem + b * BUFSZ + TBUF + lr * ROWB);
        }
    };

    auto compute = [&](int c) {
        const char* base = smem + (c & 1) * BUFSZ;
        const int swzk = (m16 & 7) << 4;
        #pragma unroll
        for (int t = 0; t < 2; ++t) {
            const int kl = w * 64 + t * 32 + kg * 8;     // f32 col in chunk
            const int a0 = m16 * ROWB + ((kl * 4) ^ swzk);
            const int a1 = a0 ^ 16;
            f32x4 x0 = *reinterpret_cast<const f32x4*>(base + a0);
            f32x4 x1 = *reinterpret_cast<const f32x4*>(base + a1);
            f32x4 m0 = *reinterpret_cast<const f32x4*>(base + TBUF + a0);
            f32x4 m1 = *reinterpret_cast<const f32x4*>(base + TBUF + a1);
            short8 fx, fxm;
            #pragma unroll
            for (int e = 0; e < 4; ++e) {
                fx[e]      = f2bf(x0[e]);
                fx[4 + e]  = f2bf(x1[e]);
                fxm[e]     = f2bf(x0[e] * m0[e]);
                fxm[4 + e] = f2bf(x1[e] * m1[e]);
            }
            accR = __builtin_amdgcn_mfma_f32_16x16x32_bf16(fxm, bR[c][t], accR, 0, 0, 0);
            accY = __builtin_amdgcn_mfma_f32_16x16x32_bf16(fx,  bW[c][t], accY, 0, 0, 0);
        }
    };

    // ---- pipeline: depth-2 prefetch, counted vmcnt, raw barriers
    stage(0, 0);
    stage(1, 1);
    #pragma unroll
    for (int c = 0; c < NCH; ++c) {
        if (c < NCH - 1) { asm volatile("s_waitcnt vmcnt(8)" ::: "memory"); }
        else             { asm volatile("s_waitcnt vmcnt(0)" ::: "memory"); }
        __builtin_amdgcn_s_barrier();            // chunk c visible to all waves
        compute(c);
        asm volatile("s_waitcnt lgkmcnt(0)" ::: "memory");  // my ds_reads done
        __builtin_amdgcn_s_barrier();            // buf[c&1] free to overwrite
        if (c + 2 < NCH) stage(c + 2, c & 1);
    }

    // ---- combine the 4 K-split partials through LDS (stride 9: no conflicts)
    float (*red)[64][9] = reinterpret_cast<float (*)[64][9]>(smem);
    #pragma unroll
    for (int q = 0; q < 4; q++) {
        red[w][l][q]     = accR[q];
        red[w][l][4 + q] = accY[q];
    }
    __syncthreads();
    if (w != 0) return;
    f32x4 sR = {0.f, 0.f, 0.f, 0.f};
    f32x4 sY = {0.f, 0.f, 0.f, 0.f};
    #pragma unroll
    for (int w2 = 0; w2 < 4; w2++) {
        #pragma unroll
        for (int q = 0; q < 4; q++) {
            sR[q] += red[w2][l][q];
            sY[q] += red[w2][l][4 + q];
        }
    }

    // epilogue: D mapping col = l&15, row = (l>>4)*4 + q
    const bool valid = (m16 < CAT);
    const float byc = valid ? b_yc[m16] : 0.f;
    float a_cls = 0.f, a_kl = 0.f;
    #pragma unroll
    for (int q = 0; q < 4; q++) {
        const int grow = r0 + kg * 4 + q;
        float z = sY[q] + byc;
        float zz = valid ? z : -1e30f;
        #pragma unroll
        for (int o = 1; o < 16; o <<= 1) zz = fmaxf(zz, __shfl_xor(zz, o, 64));
        float e = valid ? __expf(z - zz) : 0.f;
        float s = e;
        #pragma unroll
        for (int o = 1; o < 16; o <<= 1) s += __shfl_xor(s, o, 64);
        float y = e / s;
        float recon = -sR[q] * (1.f / IN);
        float cls = y * recon;
        float kl = 0.f;
        if (valid) {
            float yt = y_target[(size_t)grow * CAT + m16];
            kl = y * (logf(EPSF + y) - logf(EPSF + yt));
            out[(size_t)grow * CAT + m16] = y;
        }
        #pragma unroll
        for (int o = 1; o < 16; o <<= 1) {
            cls += __shfl_xor(cls, o, 64);
            kl  += __shfl_xor(kl, o, 64);
        }
        if (m16 == 0) { a_cls += cls; a_kl += kl; }
    }
    float vc = (m16 == 0) ? a_cls : 0.f;
    float vk = (m16 == 0) ? a_kl  : 0.f;
    vc += __shfl_xor(vc, 16, 64); vc += __shfl_xor(vc, 32, 64);
    vk += __shfl_xor(vk, 16, 64); vk += __shfl_xor(vk, 32, 64);
    if (l == 0) {
        atomicAdd(&acc[0], (double)vc);
        atomicAdd(&acc[1], (double)vk);
    }
}

__global__ void final_kernel(const double* __restrict__ acc,
                             float* __restrict__ out) {
    if (threadIdx.x == 0) {
        double loss = acc[0] / (double)B_SZ
                    + 1e-4 * (acc[1] / (double)B_SZ)
                    + (0.005 / (double)SRCN / (double)CAT / (double)CAT) * acc[2];
        out[(size_t)B_SZ * CAT] = (float)loss;
    }
}

extern "C" void kernel_launch(void* const* d_in, const int* in_sizes, int n_in,
                              void* d_out, int out_size, void* d_ws, size_t ws_size,
                              hipStream_t stream) {
    const float* x        = (const float*)d_in[0];
    const float* mask     = (const float*)d_in[1];
    const float* y_target = (const float*)d_in[2];
    const float* W_rec    = (const float*)d_in[3];
    const float* b_rec    = (const float*)d_in[4];
    const float* W_yc     = (const float*)d_in[5];
    const float* b_yc     = (const float*)d_in[6];
    float* out  = (float*)d_out;
    double* acc = (double*)d_ws;
    short* logp_t = (short*)((char*)d_ws + 256);
    short* wyc_t  = logp_t + 16 * KPAD;

    prep_kernel<<<129, 256, 0, stream>>>(W_rec, b_rec, W_yc, logp_t, wyc_t, acc);
    // 1024 row-tiles of 16 rows; async gload_lds pipeline, 2 blocks/CU
    main_kernel<<<1024, 256, 0, stream>>>(x, mask, y_target, b_yc,
                                          logp_t, wyc_t, out, acc);
    final_kernel<<<1, 64, 0, stream>>>(acc, out);
}